// Round 5
// baseline (312.524 us; speedup 1.0000x reference)
//
#include <hip/hip_runtime.h>

#define T_TOK 32768   // B*S
#define NQ    8
#define FFN   2048
#define EMB   512
#define BM    128     // tokens per block (2 wave-rows x 64)
#define BN    128     // emb cols per block (2 wave-cols x 64)
#define KSTEP 16
#define NKU   (FFN / KSTEP)   // 128

typedef __attribute__((ext_vector_type(4))) short  short4v;
typedef __attribute__((ext_vector_type(4))) float  float4v;

__device__ __forceinline__ unsigned short f2bf(float f) {
  unsigned int u = __float_as_uint(f);
  u += 0x7fffu + ((u >> 16) & 1u);
  return (unsigned short)(u >> 16);
}

__device__ __forceinline__ unsigned pk2bf(float lo, float hi) {
#if __has_builtin(__builtin_amdgcn_cvt_pk_bf16_f32)
  typedef __attribute__((ext_vector_type(2))) __bf16 bf2;
  bf2 p = __builtin_amdgcn_cvt_pk_bf16_f32(lo, hi);
  return *(unsigned*)&p;
#else
  return (unsigned)f2bf(lo) | ((unsigned)f2bf(hi) << 16);
#endif
}

// ---------------------------------------------------------------------------
// prep_all: tiled transpose W2[FFN][EMB] fp32 -> w2t[EMB][FFN] bf16,
//           plus w1t[f][i] bf16 from W1[i][f] (blockIdx.x==0 column).
// ---------------------------------------------------------------------------
__global__ void prep_all(const float* __restrict__ W1,
                         const float* __restrict__ W2,
                         unsigned short* __restrict__ w1t,
                         unsigned short* __restrict__ w2t) {
  __shared__ float t[32][33];
  const int kb = blockIdx.x * 32;   // FFN tile
  const int nb = blockIdx.y * 32;   // EMB tile
  const int c = threadIdx.x & 31, r0 = threadIdx.x >> 5;
#pragma unroll
  for (int p = 0; p < 4; ++p) {
    int r = r0 + p * 8;
    t[r][c] = W2[(size_t)(kb + r) * EMB + nb + c];
  }
  __syncthreads();
#pragma unroll
  for (int p = 0; p < 4; ++p) {
    int r = r0 + p * 8;
    w2t[(size_t)(nb + r) * FFN + kb + c] = f2bf(t[c][r]);
  }
  if (blockIdx.x == 0) {
    const int base = blockIdx.y * 1024 + threadIdx.x * 4;
#pragma unroll
    for (int e = 0; e < 4; ++e) {
      int idx = base + e;
      int f = idx >> 3, i = idx & 7;
      w1t[idx] = f2bf(W1[i * FFN + f]);
    }
  }
}

// ---------------------------------------------------------------------------
// Fused main, ZERO barriers in the K-loop:
//   GEMM1 (swapped, 16x16x16, K=8 padded to 16, bias fused into C operand)
//   produces C[f][tok] whose lane layout IS the 16x16x16 A-operand layout
//   -> relu+pack in registers -> feed GEMM2 directly. No h LDS round trip.
//   w1/b1 staged once in LDS (40960 B); w2 B-frags direct global->VGPR
//   (L2-resident, compiler free to pipeline: no barriers block hoisting).
// ---------------------------------------------------------------------------
__global__ __launch_bounds__(256, 4) void ffq_main(
    const float* __restrict__ x,
    const float* __restrict__ theta,
    const unsigned short* __restrict__ w1t,
    const float* __restrict__ b1,
    const unsigned short* __restrict__ w2t,
    const float* __restrict__ b2,
    float* __restrict__ out) {

  __shared__ unsigned short w1_lds[FFN * NQ];   // 32768 B
  __shared__ float          b1_lds[FFN];        //  8192 B -> 40960 B total

  const int tid  = threadIdx.x;
  const int wave = tid >> 6;      // 0..3
  const int lane = tid & 63;
  const int l15  = lane & 15;
  const int quad = lane >> 4;
  const int tok0 = blockIdx.x * BM;
  const int n0   = blockIdx.y * BN;
  const int wr   = wave >> 1;     // 0..1 : 64-token row group
  const int wc   = wave & 1;      // 0..1 : 64-emb col group

  // ---- one-time: stage w1t (32 KB) + b1 (8 KB) into LDS ----
#pragma unroll
  for (int i = 0; i < 8; ++i) {
    const unsigned short* g = w1t + i * 2048 + tid * 8;
    unsigned short* l = w1_lds + i * 2048 + tid * 8;
    __builtin_amdgcn_global_load_lds(
        (const __attribute__((address_space(1))) void*)g,
        (__attribute__((address_space(3))) void*)l, 16, 0, 0);
  }
#pragma unroll
  for (int i = 0; i < 2; ++i) {
    const float* g = b1 + i * 1024 + tid * 4;
    float* l = b1_lds + i * 1024 + tid * 4;
    __builtin_amdgcn_global_load_lds(
        (const __attribute__((address_space(1))) void*)g,
        (__attribute__((address_space(3))) void*)l, 16, 0, 0);
  }

  // ---- qc B1-frags (16x16x16 B layout: B[k=quad*4+i][tok=l15]) ----
  // Real K is 8 -> quads 0,1 carry data, quads 2,3 zero (pads A-garbage away).
  short4v bq[4];
#pragma unroll
  for (int mt = 0; mt < 4; ++mt) bq[mt] = (short4v){0, 0, 0, 0};
  if (quad < 2) {
    const float4 th = *(const float4*)(theta + quad * 4);
    const float c0 = __cosf(th.x), c1 = __cosf(th.y);
    const float c2 = __cosf(th.z), c3 = __cosf(th.w);
#pragma unroll
    for (int mt = 0; mt < 4; ++mt) {
      const int tok = tok0 + wr * 64 + mt * 16 + l15;
      const float4 xv = *(const float4*)(x + (size_t)tok * NQ + quad * 4);
      uint2 p;
      p.x = pk2bf(__cosf(xv.x) * c0, __cosf(xv.y) * c1);
      p.y = pk2bf(__cosf(xv.z) * c2, __cosf(xv.w) * c3);
      bq[mt] = *(short4v*)&p;
    }
  }

  // B2-frag bases: lane reads w2t[n0+wc*64+nt*16+l15][k=ku*16+quad*4 .. +3]
  const unsigned short* w2p[4];
#pragma unroll
  for (int nt = 0; nt < 4; ++nt)
    w2p[nt] = w2t + (size_t)(n0 + wc * 64 + nt * 16 + l15) * FFN + quad * 4;

  float4v acc[4][4];
#pragma unroll
  for (int i = 0; i < 4; ++i)
#pragma unroll
    for (int j = 0; j < 4; ++j)
      acc[i][j] = (float4v){0.f, 0.f, 0.f, 0.f};

  __syncthreads();   // w1/b1 staged (only barrier in the kernel)

  // ---- K loop: 128 steps of 16, no barriers ----
#pragma unroll 2
  for (int ku = 0; ku < NKU; ++ku) {
    // B2 frags for this k-slice (global, L2-hit; free to hoist/pipeline)
    short4v b2f[4];
#pragma unroll
    for (int nt = 0; nt < 4; ++nt)
      b2f[nt] = *(const short4v*)(w2p[nt] + ku * KSTEP);

    // A1 frag: w1 rows f=ku*16+l15, k=quad*4+i (quads>=2 garbage x B=0).
    // Mask keeps the read in-bounds of the 16384-short array.
    const int awoff = ((ku * 16 + l15) * 8 + quad * 4) & 16383;
    short4v aw = *(const short4v*)&w1_lds[awoff];
    // bias as MFMA C operand: C[row=f=quad*4+r] = b1[ku*16+quad*4+r]
    float4v bias = *(const float4v*)&b1_lds[ku * 16 + quad * 4];

    // GEMM1 + relu + pack -> GEMM2 A-frags (pure registers)
    short4v a2[4];
#pragma unroll
    for (int mt = 0; mt < 4; ++mt) {
      float4v c1 = __builtin_amdgcn_mfma_f32_16x16x16bf16_1k(
          aw, bq[mt], bias, 0, 0, 0);
      float v0 = c1[0] > 0.f ? c1[0] : 0.f;
      float v1 = c1[1] > 0.f ? c1[1] : 0.f;
      float v2 = c1[2] > 0.f ? c1[2] : 0.f;
      float v3 = c1[3] > 0.f ? c1[3] : 0.f;
      uint2 p;
      p.x = pk2bf(v0, v1);
      p.y = pk2bf(v2, v3);
      a2[mt] = *(short4v*)&p;
    }

#pragma unroll
    for (int mt = 0; mt < 4; ++mt)
#pragma unroll
      for (int nt = 0; nt < 4; ++nt)
        acc[mt][nt] = __builtin_amdgcn_mfma_f32_16x16x16bf16_1k(
            a2[mt], b2f[nt], acc[mt][nt], 0, 0, 0);
  }

  // ---- epilogue: + b2, fp32 store ----
#pragma unroll
  for (int nt = 0; nt < 4; ++nt) {
    const int col = n0 + wc * 64 + nt * 16 + l15;
    const float bv = b2[col];
#pragma unroll
    for (int mt = 0; mt < 4; ++mt) {
      const int row0 = tok0 + wr * 64 + mt * 16 + quad * 4;
#pragma unroll
      for (int r = 0; r < 4; ++r) {
        out[(size_t)(row0 + r) * EMB + col] = acc[mt][nt][r] + bv;
      }
    }
  }
}

extern "C" void kernel_launch(void* const* d_in, const int* in_sizes, int n_in,
                              void* d_out, int out_size, void* d_ws, size_t ws_size,
                              hipStream_t stream) {
  const float* x     = (const float*)d_in[0];
  const float* theta = (const float*)d_in[1];
  const float* W1    = (const float*)d_in[2];
  const float* b1    = (const float*)d_in[3];
  const float* W2    = (const float*)d_in[4];
  const float* b2    = (const float*)d_in[5];
  float* out = (float*)d_out;

  unsigned short* w1t = (unsigned short*)d_ws;       // 16384 bf16
  unsigned short* w2t = w1t + FFN * NQ;              // 1048576 bf16

  prep_all<<<dim3(FFN / 32, EMB / 32), 256, 0, stream>>>(W1, W2, w1t, w2t);

  dim3 grid(T_TOK / BM, EMB / BN);  // (256, 4)
  ffq_main<<<grid, 256, 0, stream>>>(x, theta, w1t, b1, w2t, b2, out);
}

// Round 6
// 174.070 us; speedup vs baseline: 1.7954x; 1.7954x over previous
//
#include <hip/hip_runtime.h>

#define T_TOK 32768   // B*S
#define NQ    8
#define FFN   2048
#define EMB   512
#define BM    128
#define BN    128
#define BK    64
#define NCHUNK (FFN / BK)   // 32
#define HPAD  72            // h_lds row stride in shorts (144 B, 16B-aligned)

typedef __attribute__((ext_vector_type(8))) short  short8;
typedef __attribute__((ext_vector_type(4))) float  float4v;

__device__ __forceinline__ unsigned short f2bf(float f) {
  unsigned int u = __float_as_uint(f);
  u += 0x7fffu + ((u >> 16) & 1u);
  return (unsigned short)(u >> 16);
}

__device__ __forceinline__ unsigned pk2bf(float lo, float hi) {
#if __has_builtin(__builtin_amdgcn_cvt_pk_bf16_f32)
  typedef __attribute__((ext_vector_type(2))) __bf16 bf2;
  bf2 p = __builtin_amdgcn_cvt_pk_bf16_f32(lo, hi);
  return *(unsigned*)&p;
#else
  return (unsigned)f2bf(lo) | ((unsigned)f2bf(hi) << 16);
#endif
}

// ---------------------------------------------------------------------------
// prep_all: tiled transpose W2[FFN][EMB] fp32 -> w2t[EMB][FFN] bf16,
//           plus w1t[f][i] bf16 from W1[i][f] (blockIdx.x==0 column).
// ---------------------------------------------------------------------------
__global__ void prep_all(const float* __restrict__ W1,
                         const float* __restrict__ W2,
                         unsigned short* __restrict__ w1t,
                         unsigned short* __restrict__ w2t) {
  __shared__ float t[32][33];
  const int kb = blockIdx.x * 32;   // FFN tile
  const int nb = blockIdx.y * 32;   // EMB tile
  const int c = threadIdx.x & 31, r0 = threadIdx.x >> 5;
#pragma unroll
  for (int p = 0; p < 4; ++p) {
    int r = r0 + p * 8;
    t[r][c] = W2[(size_t)(kb + r) * EMB + nb + c];
  }
  __syncthreads();
#pragma unroll
  for (int p = 0; p < 4; ++p) {
    int r = r0 + p * 8;
    w2t[(size_t)(nb + r) * FFN + kb + c] = f2bf(t[c][r]);
  }
  if (blockIdx.x == 0) {
    const int base = blockIdx.y * 1024 + threadIdx.x * 4;
#pragma unroll
    for (int e = 0; e < 4; ++e) {
      int idx = base + e;
      int f = idx >> 3, i = idx & 7;
      w1t[idx] = f2bf(W1[i * FFN + f]);
    }
  }
}

// ---------------------------------------------------------------------------
// Fused main (R3 structure at 2x occupancy):
//   LDS = h tile (18.4K) + w2 chunk (16K) only -> 34816 B -> 4 blocks/CU,
//   16 waves/CU. w1/b1 frags read straight from global (L1-resident, quads
//   broadcast); issued BEFORE stage_w2 so their vmcnt retires without
//   draining the w2 stage queue.
// ---------------------------------------------------------------------------
__global__ __launch_bounds__(256, 4) void ffq_main(
    const float* __restrict__ x,
    const float* __restrict__ theta,
    const unsigned short* __restrict__ w1t,
    const float* __restrict__ b1,
    const unsigned short* __restrict__ w2t,
    const float* __restrict__ b2,
    float* __restrict__ out) {

  __shared__ unsigned short h_lds[BM][HPAD];     // 18432 B
  __shared__ unsigned short w2_lds[BN * BK];     // 16384 B -> 34816 total

  const int tid  = threadIdx.x;
  const int wave = tid >> 6;
  const int lane = tid & 63;
  const int l15  = lane & 15;
  const int quad = lane >> 4;
  const int tok0 = blockIdx.x * BM;
  const int n0   = blockIdx.y * BN;
  const int wr   = wave >> 1;   // GEMM2 wave row (64 tokens)
  const int wc   = wave & 1;    // GEMM2 wave col (64 emb)

  // ---- qc B-frags for GEMM1 (this wave's 32 tokens), computed once ----
  float cth[8];
  {
    const float4* tp = (const float4*)theta;
    float4 t0 = tp[0], t1 = tp[1];
    cth[0] = __cosf(t0.x); cth[1] = __cosf(t0.y);
    cth[2] = __cosf(t0.z); cth[3] = __cosf(t0.w);
    cth[4] = __cosf(t1.x); cth[5] = __cosf(t1.y);
    cth[6] = __cosf(t1.z); cth[7] = __cosf(t1.w);
  }
  short8 bq[2];
#pragma unroll
  for (int g = 0; g < 2; ++g) {
    short8 v = (short8){0,0,0,0,0,0,0,0};
    if (lane < 16) {
      int tok = tok0 + 32 * wave + 16 * g + lane;
      const float4* xp = (const float4*)(x + (size_t)tok * NQ);
      float4 x0 = xp[0], x1 = xp[1];
      float q0 = __cosf(x0.x) * cth[0], q1 = __cosf(x0.y) * cth[1];
      float q2 = __cosf(x0.z) * cth[2], q3 = __cosf(x0.w) * cth[3];
      float q4 = __cosf(x1.x) * cth[4], q5 = __cosf(x1.y) * cth[5];
      float q6 = __cosf(x1.z) * cth[6], q7 = __cosf(x1.w) * cth[7];
      uint4 uu;
      uu.x = pk2bf(q0, q1); uu.y = pk2bf(q2, q3);
      uu.z = pk2bf(q4, q5); uu.w = pk2bf(q6, q7);
      v = *(short8*)&uu;
    }
    bq[g] = v;
  }

  float4v acc[4][4];
#pragma unroll
  for (int i = 0; i < 4; ++i)
#pragma unroll
    for (int j = 0; j < 4; ++j)
      acc[i][j] = (float4v){0.f, 0.f, 0.f, 0.f};

  for (int kc = 0; kc < NCHUNK; ++kc) {
    const int k0 = kc * BK;

    __syncthreads();  // prev chunk's h/w2 readers done

    // ---- w1/b1 frags from global FIRST (vmcnt retires before w2 stages) ----
    short8 aw[4];
    float4 bias[4];
#pragma unroll
    for (int kt = 0; kt < 4; ++kt) {
      // address depends on l15 only -> quads broadcast same 16B; L1-resident
      aw[kt]   = *(const short8*)(w1t + (size_t)(k0 + kt * 16 + l15) * NQ);
      bias[kt] = *(const float4*)(b1 + k0 + kt * 16 + quad * 4);
    }

    // ---- stage w2 chunk -> w2_lds, 16B XOR-swizzled ----
    {
      const int r = tid >> 3;   // row within 32-row group
      const int c = tid & 7;    // stored 16B-chunk index
#pragma unroll
      for (int issue = 0; issue < 4; ++issue) {
        const int row    = issue * 32 + r;        // local n, 0..127
        const int gchunk = c ^ (row & 7);
        const unsigned short* g =
            w2t + (size_t)(n0 + row) * FFN + k0 + gchunk * 8;
        unsigned short* l = &w2_lds[issue * 2048 + tid * 8];
        __builtin_amdgcn_global_load_lds(
            (const __attribute__((address_space(1))) void*)g,
            (__attribute__((address_space(3))) void*)l, 16, 0, 0);
      }
    }

    // ---- GEMM1: C[f = quad*4+r][tok = l15] -> packed b64 h-writes ----
#pragma unroll
    for (int kt = 0; kt < 4; ++kt) {
      float4v c0 = (float4v){0.f, 0.f, 0.f, 0.f};
      float4v c1 = (float4v){0.f, 0.f, 0.f, 0.f};
      c0 = __builtin_amdgcn_mfma_f32_16x16x32_bf16(aw[kt], bq[0], c0, 0, 0, 0);
      c1 = __builtin_amdgcn_mfma_f32_16x16x32_bf16(aw[kt], bq[1], c1, 0, 0, 0);
      float v0[4], v1[4];
#pragma unroll
      for (int r = 0; r < 4; ++r) {
        float a0 = c0[r] + bias[kt][r]; v0[r] = a0 > 0.f ? a0 : 0.f;
        float a1 = c1[r] + bias[kt][r]; v1[r] = a1 > 0.f ? a1 : 0.f;
      }
      uint2 p0, p1;
      p0.x = pk2bf(v0[0], v0[1]); p0.y = pk2bf(v0[2], v0[3]);
      p1.x = pk2bf(v1[0], v1[1]); p1.y = pk2bf(v1[2], v1[3]);
      *((uint2*)&h_lds[32 * wave + l15][kt * 16 + quad * 4])      = p0;
      *((uint2*)&h_lds[32 * wave + 16 + l15][kt * 16 + quad * 4]) = p1;
    }

    __syncthreads();  // h visible; vmcnt(0) drained -> w2_lds ready

    // ---- GEMM2: acc += h_tile @ w2_chunk (both from LDS) ----
#pragma unroll
    for (int ks = 0; ks < 2; ++ks) {
      short8 af[4], bf[4];
#pragma unroll
      for (int mt = 0; mt < 4; ++mt)
        af[mt] = *(const short8*)&h_lds[wr * 64 + mt * 16 + l15]
                                       [ks * 32 + quad * 8];
#pragma unroll
      for (int nt = 0; nt < 4; ++nt) {
        const int n  = wc * 64 + nt * 16 + l15;
        const int sc = (ks * 4 + quad) ^ (n & 7);   // undo XOR swizzle
        bf[nt] = *(const short8*)&w2_lds[n * BK + sc * 8];
      }
#pragma unroll
      for (int mt = 0; mt < 4; ++mt)
#pragma unroll
        for (int nt = 0; nt < 4; ++nt)
          acc[mt][nt] = __builtin_amdgcn_mfma_f32_16x16x32_bf16(
              af[mt], bf[nt], acc[mt][nt], 0, 0, 0);
    }
  }

  // ---- epilogue: + b2, fp32 store ----
#pragma unroll
  for (int nt = 0; nt < 4; ++nt) {
    const int col = n0 + wc * 64 + nt * 16 + l15;
    const float bv = b2[col];
#pragma unroll
    for (int mt = 0; mt < 4; ++mt) {
      const int row0 = tok0 + wr * 64 + mt * 16 + quad * 4;
#pragma unroll
      for (int r = 0; r < 4; ++r) {
        out[(size_t)(row0 + r) * EMB + col] = acc[mt][nt][r] + bv;
      }
    }
  }
}

extern "C" void kernel_launch(void* const* d_in, const int* in_sizes, int n_in,
                              void* d_out, int out_size, void* d_ws, size_t ws_size,
                              hipStream_t stream) {
  const float* x     = (const float*)d_in[0];
  const float* theta = (const float*)d_in[1];
  const float* W1    = (const float*)d_in[2];
  const float* b1    = (const float*)d_in[3];
  const float* W2    = (const float*)d_in[4];
  const float* b2    = (const float*)d_in[5];
  float* out = (float*)d_out;

  unsigned short* w1t = (unsigned short*)d_ws;       // 16384 bf16
  unsigned short* w2t = w1t + FFN * NQ;              // 1048576 bf16

  prep_all<<<dim3(FFN / 32, EMB / 32), 256, 0, stream>>>(W1, W2, w1t, w2t);

  dim3 grid(T_TOK / BM, EMB / BN);  // (256, 4) = 1024 blocks = 4/CU
  ffq_main<<<grid, 256, 0, stream>>>(x, theta, w1t, b1, w2t, b2, out);
}